// Round 15
// baseline (103.592 us; speedup 1.0000x reference)
//
#include <hip/hip_runtime.h>
#include <math.h>

#define M_  2
#define B_  256
#define L_  1024
#define K_  4
#define S_  20
#define NR_ 100
#define NTERM 7   // Taylor terms T_1..T_7 ; ||mu*Q||inf <= 0.13 -> rem ~2e-11

__device__ __forceinline__ float softplusf(float x) {
    return x > 20.0f ? x : log1pf(expf(x));
}

// ---------------------------------------------------------------------------
// Kernel 1: per (m,k): normalized Q, Taylor T_n = Q^n/n! (registers), then
// P[m,r,k] = I + sum_n mu_r^n T_n for ALL 100 r. 8 blocks, 512 threads.
// ---------------------------------------------------------------------------
__global__ __launch_bounds__(512)
void pmat_kernel(const float* __restrict__ tauk,   // (M,NR)
                 const float* __restrict__ exch,   // (M,K,S,S)
                 const float* __restrict__ equil,  // (M,K,S)
                 const float* __restrict__ pmrk,   // (M,K)
                 float*       __restrict__ Pws)    // (M,NR,K,400)
{
    __shared__ float sQ[400];
    __shared__ float sT[2][400];
    __shared__ float sRow[20];

    const int blk = blockIdx.x;          // mm*K_ + kk
    const int kk = blk % K_;
    const int mm = blk / K_;
    const int tid = threadIdx.x;
    const bool act = tid < 400;
    const int i = tid / 20;
    const int j = tid - i * 20;

    float p[20];
    float Q0 = 0.0f, rowsum = 0.0f;
    float tn[NTERM];

    if (act) {
        const float* eq = equil + (mm * K_ + kk) * S_;
        float mx = eq[0];
        #pragma unroll
        for (int z = 1; z < 20; ++z) mx = fmaxf(mx, eq[z]);
        float s = 0.0f;
        #pragma unroll
        for (int z = 0; z < 20; ++z) { p[z] = expf(eq[z] - mx); s += p[z]; }
        const float inv = 1.0f / s;
        #pragma unroll
        for (int z = 0; z < 20; ++z) p[z] *= inv;

        const float* Kx = exch + (mm * K_ + kk) * S_ * S_;
        float R = (i == j) ? 0.0f : softplusf(0.5f * (Kx[i * 20 + j] + Kx[j * 20 + i]));
        Q0 = R * p[j];
        sQ[tid] = Q0;
    }
    __syncthreads();

    if (act) {
        rowsum = 0.0f;
        #pragma unroll
        for (int z = 0; z < 20; ++z) rowsum += sQ[i * 20 + z];
        if (j == 0) sRow[i] = rowsum;
    }
    __syncthreads();

    if (act) {
        float mue = 0.0f;
        #pragma unroll
        for (int z = 0; z < 20; ++z) mue += p[z] * sRow[z];
        float q = (Q0 - ((i == j) ? rowsum : 0.0f)) / fmaxf(mue, 1e-16f);
        sQ[tid] = q;
        sT[0][tid] = q;
        tn[0] = q;                       // T_1 = Q
    }
    __syncthreads();

    int cur = 0;
    for (int n = 2; n <= NTERM; ++n) {
        if (act) {
            float acc = 0.0f;
            #pragma unroll
            for (int z = 0; z < 20; ++z) acc += sT[cur][i * 20 + z] * sQ[z * 20 + j];
            acc /= (float)n;
            tn[n - 1] = acc;             // T_n = Q^n / n!
            sT[cur ^ 1][tid] = acc;
        }
        __syncthreads();
        cur ^= 1;
    }

    if (act) {
        const float pm = softplusf(pmrk[mm * K_ + kk]);
        const float idn = (i == j) ? 1.0f : 0.0f;
        for (int rr = 0; rr < NR_; ++rr) {
            const float mu = softplusf(tauk[mm * NR_ + rr]) * pm;
            float a = idn;
            float mp = mu;
            #pragma unroll
            for (int n = 0; n < NTERM; ++n) { a = fmaf(mp, tn[n], a); mp *= mu; }
            Pws[((size_t)(mm * NR_ + rr) * K_ + kk) * 400 + tid] = a;
        }
    }
}

// ---------------------------------------------------------------------------
// Kernel 2: R10's proven einsum VERBATIM except stores go THROUGH L2
// (single-variable NT ablation; R12->R13 showed NT cost ~19% even though
// writes are streaming -- L2 write-combines and schedules HBM bursts).
// Block owns 256 rows staged in LDS (20 KB) + P (6.4 KB); ONE barrier;
// thread (rg, t) computes 16 rows x 4 cols, acc[16]; 2048 blocks.
// ---------------------------------------------------------------------------
#define SPANR 256
#define TPB3  320

__device__ __forceinline__ void fma4(float4& a, float s, const float4& p) {
    a.x = fmaf(s, p.x, a.x);
    a.y = fmaf(s, p.y, a.y);
    a.z = fmaf(s, p.z, a.z);
    a.w = fmaf(s, p.w, a.w);
}

__global__ __launch_bounds__(TPB3)
void einsum_kernel(const float* __restrict__ inp,  // (M,B,L,S)
                   const float* __restrict__ Pws,  // (M,NR,K,400)
                   const int*   __restrict__ ridx, // (M,B)
                   float*       __restrict__ out)  // (M,B,L,K*S)
{
    __shared__ float Pl[K_ * 400];          // 6400 B   [k][z][s]
    __shared__ float inL[SPANR * 20];       // 20480 B

    const int bx      = blockIdx.x;
    const int quarter = bx & 3;            // L_/SPANR = 4
    const int mb      = bx >> 2;           // 0..511
    const int mm      = mb >> 8;
    const int tid     = threadIdx.x;
    const int t       = tid % 20;
    const int rg      = tid / 20;          // 0..15
    const int k       = t / 5;
    const int s0      = (t % 5) * 4;

    const int r = ridx[mb];                // block-uniform

    // ---- stage P (1600 floats) and 256 input rows (5120 floats), coalesced ----
    {
        const float4* Psrc = (const float4*)(Pws + ((size_t)(mm * NR_ + r) * K_) * 400);
        float4* Pd = (float4*)Pl;
        Pd[tid] = Psrc[tid];
        if (tid < 80) Pd[320 + tid] = Psrc[320 + tid];

        const size_t row0g = (size_t)mb * L_ + (size_t)quarter * SPANR;
        const float4* Isrc = (const float4*)(inp + row0g * 20);
        float4* Id = (float4*)inL;
        #pragma unroll
        for (int q = 0; q < 4; ++q) Id[tid + q * TPB3] = Isrc[tid + q * TPB3];
    }
    __syncthreads();                       // the ONLY barrier

    const size_t row0 = (size_t)mb * L_ + (size_t)quarter * SPANR;
    float* ob = out + row0 * 80 + k * 20 + s0;
    const float* Pk = Pl + k * 400 + s0;   // + z*20 per z

    float4 acc[16];
    #pragma unroll
    for (int rr = 0; rr < 16; ++rr) acc[rr] = make_float4(0.f, 0.f, 0.f, 0.f);

    #pragma unroll
    for (int z4 = 0; z4 < 5; ++z4) {
        const float4 p0 = *(const float4*)(Pk + (z4 * 4 + 0) * 20);
        const float4 p1 = *(const float4*)(Pk + (z4 * 4 + 1) * 20);
        const float4 p2 = *(const float4*)(Pk + (z4 * 4 + 2) * 20);
        const float4 p3 = *(const float4*)(Pk + (z4 * 4 + 3) * 20);
        #pragma unroll
        for (int rr = 0; rr < 16; ++rr) {
            const int l = rg + rr * 16;
            const float4 av = *(const float4*)(inL + l * 20 + z4 * 4);
            fma4(acc[rr], av.x, p0);
            fma4(acc[rr], av.y, p1);
            fma4(acc[rr], av.z, p2);
            fma4(acc[rr], av.w, p3);
        }
    }

    #pragma unroll
    for (int rr = 0; rr < 16; ++rr) {
        const int l = rg + rr * 16;
        *(float4*)(ob + (size_t)l * 80) = acc[rr];   // through L2 (write-combine)
    }
}

// ---------------------------------------------------------------------------
extern "C" void kernel_launch(void* const* d_in, const int* in_sizes, int n_in,
                              void* d_out, int out_size, void* d_ws, size_t ws_size,
                              hipStream_t stream) {
    const float* inp   = (const float*)d_in[0];  // (M,B,L,S)
    const float* tauk  = (const float*)d_in[1];  // (M,NR)
    const float* exch  = (const float*)d_in[2];  // (M,K,S,S)
    const float* equil = (const float*)d_in[3];  // (M,K,S)
    const float* pmrk  = (const float*)d_in[4];  // (M,K)
    const int*   ridx  = (const int*)d_in[5];    // (M,B)
    float* outp = (float*)d_out;

    float* Pws = (float*)d_ws;                   // M*NR*K*400*4 = 1.28 MB

    pmat_kernel<<<M_ * K_, 512, 0, stream>>>(tauk, exch, equil, pmrk, Pws);
    einsum_kernel<<<M_ * B_ * (L_ / SPANR), TPB3, 0, stream>>>(inp, Pws, ridx, outp);
}

// Round 16
// 101.886 us; speedup vs baseline: 1.0167x; 1.0167x over previous
//
#include <hip/hip_runtime.h>
#include <math.h>

#define M_  2
#define B_  256
#define L_  1024
#define K_  4
#define S_  20
#define NR_ 100
#define NTERM 7   // Taylor terms T_1..T_7 ; ||mu*Q||inf <= 0.13 -> rem ~2e-11

typedef float f32x4_t __attribute__((ext_vector_type(4)));

__device__ __forceinline__ float softplusf(float x) {
    return x > 20.0f ? x : log1pf(expf(x));
}

// ---------------------------------------------------------------------------
// Kernel 1: per (m,k): normalized Q, Taylor T_n = Q^n/n! (registers), then
// P[m,r,k] = I + sum_n mu_r^n T_n for ALL 100 r. 8 blocks, 512 threads.
// (~10us; replaces qpow+pbuild+one launch gap at parity.)
// ---------------------------------------------------------------------------
__global__ __launch_bounds__(512)
void pmat_kernel(const float* __restrict__ tauk,   // (M,NR)
                 const float* __restrict__ exch,   // (M,K,S,S)
                 const float* __restrict__ equil,  // (M,K,S)
                 const float* __restrict__ pmrk,   // (M,K)
                 float*       __restrict__ Pws)    // (M,NR,K,400)
{
    __shared__ float sQ[400];
    __shared__ float sT[2][400];
    __shared__ float sRow[20];

    const int blk = blockIdx.x;          // mm*K_ + kk
    const int kk = blk % K_;
    const int mm = blk / K_;
    const int tid = threadIdx.x;
    const bool act = tid < 400;
    const int i = tid / 20;
    const int j = tid - i * 20;

    float p[20];
    float Q0 = 0.0f, rowsum = 0.0f;
    float tn[NTERM];

    if (act) {
        const float* eq = equil + (mm * K_ + kk) * S_;
        float mx = eq[0];
        #pragma unroll
        for (int z = 1; z < 20; ++z) mx = fmaxf(mx, eq[z]);
        float s = 0.0f;
        #pragma unroll
        for (int z = 0; z < 20; ++z) { p[z] = expf(eq[z] - mx); s += p[z]; }
        const float inv = 1.0f / s;
        #pragma unroll
        for (int z = 0; z < 20; ++z) p[z] *= inv;

        const float* Kx = exch + (mm * K_ + kk) * S_ * S_;
        float R = (i == j) ? 0.0f : softplusf(0.5f * (Kx[i * 20 + j] + Kx[j * 20 + i]));
        Q0 = R * p[j];
        sQ[tid] = Q0;
    }
    __syncthreads();

    if (act) {
        rowsum = 0.0f;
        #pragma unroll
        for (int z = 0; z < 20; ++z) rowsum += sQ[i * 20 + z];
        if (j == 0) sRow[i] = rowsum;
    }
    __syncthreads();

    if (act) {
        float mue = 0.0f;
        #pragma unroll
        for (int z = 0; z < 20; ++z) mue += p[z] * sRow[z];
        float q = (Q0 - ((i == j) ? rowsum : 0.0f)) / fmaxf(mue, 1e-16f);
        sQ[tid] = q;
        sT[0][tid] = q;
        tn[0] = q;                       // T_1 = Q
    }
    __syncthreads();

    int cur = 0;
    for (int n = 2; n <= NTERM; ++n) {
        if (act) {
            float acc = 0.0f;
            #pragma unroll
            for (int z = 0; z < 20; ++z) acc += sT[cur][i * 20 + z] * sQ[z * 20 + j];
            acc /= (float)n;
            tn[n - 1] = acc;             // T_n = Q^n / n!
            sT[cur ^ 1][tid] = acc;
        }
        __syncthreads();
        cur ^= 1;
    }

    if (act) {
        const float pm = softplusf(pmrk[mm * K_ + kk]);
        const float idn = (i == j) ? 1.0f : 0.0f;
        for (int rr = 0; rr < NR_; ++rr) {
            const float mu = softplusf(tauk[mm * NR_ + rr]) * pm;
            float a = idn;
            float mp = mu;
            #pragma unroll
            for (int n = 0; n < NTERM; ++n) { a = fmaf(mp, tn[n], a); mp *= mu; }
            Pws[((size_t)(mm * NR_ + rr) * K_ + kk) * 400 + tid] = a;
        }
    }
}

// ---------------------------------------------------------------------------
// Kernel 2: R10's champion einsum VERBATIM (NT stores restored -- R15's
// single-variable ablation showed through-L2 stores cost ~+45us on this
// coalesced-burst store pattern; NT is load-bearing here).
// Block owns 256 rows staged in LDS (20 KB) + P (6.4 KB); ONE barrier;
// thread (rg, t) computes 16 rows x 4 cols, acc[16]; 2048 blocks.
// ---------------------------------------------------------------------------
#define SPANR 256
#define TPB3  320

__device__ __forceinline__ void fma4(float4& a, float s, const float4& p) {
    a.x = fmaf(s, p.x, a.x);
    a.y = fmaf(s, p.y, a.y);
    a.z = fmaf(s, p.z, a.z);
    a.w = fmaf(s, p.w, a.w);
}

__device__ __forceinline__ void nt_store4(float* dst, const float4& v) {
    f32x4_t w;
    w.x = v.x; w.y = v.y; w.z = v.z; w.w = v.w;
    __builtin_nontemporal_store(w, (f32x4_t*)dst);
}

__global__ __launch_bounds__(TPB3)
void einsum_kernel(const float* __restrict__ inp,  // (M,B,L,S)
                   const float* __restrict__ Pws,  // (M,NR,K,400)
                   const int*   __restrict__ ridx, // (M,B)
                   float*       __restrict__ out)  // (M,B,L,K*S)
{
    __shared__ float Pl[K_ * 400];          // 6400 B   [k][z][s]
    __shared__ float inL[SPANR * 20];       // 20480 B

    const int bx      = blockIdx.x;
    const int quarter = bx & 3;            // L_/SPANR = 4
    const int mb      = bx >> 2;           // 0..511
    const int mm      = mb >> 8;
    const int tid     = threadIdx.x;
    const int t       = tid % 20;
    const int rg      = tid / 20;          // 0..15
    const int k       = t / 5;
    const int s0      = (t % 5) * 4;

    const int r = ridx[mb];                // block-uniform

    // ---- stage P (1600 floats) and 256 input rows (5120 floats), coalesced ----
    {
        const float4* Psrc = (const float4*)(Pws + ((size_t)(mm * NR_ + r) * K_) * 400);
        float4* Pd = (float4*)Pl;
        Pd[tid] = Psrc[tid];
        if (tid < 80) Pd[320 + tid] = Psrc[320 + tid];

        const size_t row0g = (size_t)mb * L_ + (size_t)quarter * SPANR;
        const float4* Isrc = (const float4*)(inp + row0g * 20);
        float4* Id = (float4*)inL;
        #pragma unroll
        for (int q = 0; q < 4; ++q) Id[tid + q * TPB3] = Isrc[tid + q * TPB3];
    }
    __syncthreads();                       // the ONLY barrier

    const size_t row0 = (size_t)mb * L_ + (size_t)quarter * SPANR;
    float* ob = out + row0 * 80 + k * 20 + s0;
    const float* Pk = Pl + k * 400 + s0;   // + z*20 per z

    float4 acc[16];
    #pragma unroll
    for (int rr = 0; rr < 16; ++rr) acc[rr] = make_float4(0.f, 0.f, 0.f, 0.f);

    #pragma unroll
    for (int z4 = 0; z4 < 5; ++z4) {
        const float4 p0 = *(const float4*)(Pk + (z4 * 4 + 0) * 20);
        const float4 p1 = *(const float4*)(Pk + (z4 * 4 + 1) * 20);
        const float4 p2 = *(const float4*)(Pk + (z4 * 4 + 2) * 20);
        const float4 p3 = *(const float4*)(Pk + (z4 * 4 + 3) * 20);
        #pragma unroll
        for (int rr = 0; rr < 16; ++rr) {
            const int l = rg + rr * 16;
            const float4 av = *(const float4*)(inL + l * 20 + z4 * 4);
            fma4(acc[rr], av.x, p0);
            fma4(acc[rr], av.y, p1);
            fma4(acc[rr], av.z, p2);
            fma4(acc[rr], av.w, p3);
        }
    }

    #pragma unroll
    for (int rr = 0; rr < 16; ++rr) {
        const int l = rg + rr * 16;
        nt_store4(ob + (size_t)l * 80, acc[rr]);
    }
}

// ---------------------------------------------------------------------------
extern "C" void kernel_launch(void* const* d_in, const int* in_sizes, int n_in,
                              void* d_out, int out_size, void* d_ws, size_t ws_size,
                              hipStream_t stream) {
    const float* inp   = (const float*)d_in[0];  // (M,B,L,S)
    const float* tauk  = (const float*)d_in[1];  // (M,NR)
    const float* exch  = (const float*)d_in[2];  // (M,K,S,S)
    const float* equil = (const float*)d_in[3];  // (M,K,S)
    const float* pmrk  = (const float*)d_in[4];  // (M,K)
    const int*   ridx  = (const int*)d_in[5];    // (M,B)
    float* outp = (float*)d_out;

    float* Pws = (float*)d_ws;                   // M*NR*K*400*4 = 1.28 MB

    pmat_kernel<<<M_ * K_, 512, 0, stream>>>(tauk, exch, equil, pmrk, Pws);
    einsum_kernel<<<M_ * B_ * (L_ / SPANR), TPB3, 0, stream>>>(inp, Pws, ridx, outp);
}

// Round 17
// 58.048 us; speedup vs baseline: 1.7846x; 1.7552x over previous
//
#include <hip/hip_runtime.h>
#include <math.h>

#define M_  2
#define B_  256
#define L_  1024
#define K_  4
#define S_  20
#define NR_ 100
#define NTERM 7   // Taylor terms T_1..T_7 ; ||mu*Q||inf <= 0.13 -> rem ~2e-11

typedef float f32x4_t __attribute__((ext_vector_type(4)));

__device__ __forceinline__ float softplusf(float x) {
    return x > 20.0f ? x : log1pf(expf(x));
}

// ---------------------------------------------------------------------------
// Kernel 1: per (m,k), compute normalized Q, store T_n = Q^n/n!, n=1..NTERM.
// 8 blocks (serial chain lives here only). [R16 lesson: do NOT fuse the
// 100-r loop into this 8-block kernel -- latency-bound on 8 CUs, ~+44us.]
// ---------------------------------------------------------------------------
__global__ __launch_bounds__(512)
void qpow_kernel(const float* __restrict__ exch,   // (M,K,S,S)
                 const float* __restrict__ equil,  // (M,K,S)
                 float*       __restrict__ Qpow)   // (M,K,NTERM,400)
{
    __shared__ float sQ[400];
    __shared__ float sT[2][400];
    __shared__ float sRow[20];

    const int blk = blockIdx.x;          // mm*K_ + kk
    const int kk = blk % K_;
    const int mm = blk / K_;
    const int tid = threadIdx.x;
    const bool act = tid < 400;
    const int i = tid / 20;
    const int j = tid - i * 20;

    float p[20];
    float Q0 = 0.0f, rowsum = 0.0f;

    if (act) {
        const float* eq = equil + (mm * K_ + kk) * S_;
        float mx = eq[0];
        #pragma unroll
        for (int z = 1; z < 20; ++z) mx = fmaxf(mx, eq[z]);
        float s = 0.0f;
        #pragma unroll
        for (int z = 0; z < 20; ++z) { p[z] = expf(eq[z] - mx); s += p[z]; }
        const float inv = 1.0f / s;
        #pragma unroll
        for (int z = 0; z < 20; ++z) p[z] *= inv;

        const float* Kx = exch + (mm * K_ + kk) * S_ * S_;
        float R = (i == j) ? 0.0f : softplusf(0.5f * (Kx[i * 20 + j] + Kx[j * 20 + i]));
        Q0 = R * p[j];
        sQ[tid] = Q0;
    }
    __syncthreads();

    if (act) {
        rowsum = 0.0f;
        #pragma unroll
        for (int z = 0; z < 20; ++z) rowsum += sQ[i * 20 + z];
        if (j == 0) sRow[i] = rowsum;
    }
    __syncthreads();

    float* Tout = Qpow + (size_t)blk * (NTERM * 400);
    if (act) {
        float mue = 0.0f;
        #pragma unroll
        for (int z = 0; z < 20; ++z) mue += p[z] * sRow[z];
        float q = (Q0 - ((i == j) ? rowsum : 0.0f)) / fmaxf(mue, 1e-16f);
        sQ[tid] = q;
        sT[0][tid] = q;
        Tout[tid] = q;       // T_1 = Q
    }
    __syncthreads();

    int cur = 0;
    for (int n = 2; n <= NTERM; ++n) {
        if (act) {
            float acc = 0.0f;
            #pragma unroll
            for (int z = 0; z < 20; ++z) acc += sT[cur][i * 20 + z] * sQ[z * 20 + j];
            acc /= (float)n;
            sT[cur ^ 1][tid] = acc;
            Tout[(n - 1) * 400 + tid] = acc;   // T_n = Q^n / n!
        }
        __syncthreads();
        cur ^= 1;
    }
}

// ---------------------------------------------------------------------------
// Kernel 2: P[m,r,k] = I + sum_n mu^n T_n  (linear combo, no matmuls).
// 800 blocks -- wide and parallel; this split beats the fused 8-block
// producer by ~44us (R10 vs R16 A/B).
// ---------------------------------------------------------------------------
__global__ __launch_bounds__(512)
void pbuild_kernel(const float* __restrict__ Qpow,  // (M,K,NTERM,400)
                   const float* __restrict__ tauk,  // (M,NR)
                   const float* __restrict__ pmrk,  // (M,K)
                   float*       __restrict__ Pws)   // (M,NR,K,400)
{
    const int blk = blockIdx.x;          // mm*NR*K + rr*K + kk
    const int kk = blk % K_;
    const int rr = (blk / K_) % NR_;
    const int mm = blk / (K_ * NR_);
    const int tid = threadIdx.x;
    if (tid >= 400) return;

    const float mu = softplusf(tauk[mm * NR_ + rr]) * softplusf(pmrk[mm * K_ + kk]);
    const float* T = Qpow + ((size_t)(mm * K_ + kk) * NTERM) * 400 + tid;

    float acc = (tid % 21 == 0) ? 1.0f : 0.0f;   // identity
    float mp = mu;
    #pragma unroll
    for (int n = 0; n < NTERM; ++n) { acc = fmaf(mp, T[n * 400], acc); mp *= mu; }
    Pws[(size_t)blk * 400 + tid] = acc;
}

// ---------------------------------------------------------------------------
// Kernel 3: R10's champion einsum, verbatim, + XCD-aware bijective block
// swizzle (2048 blocks % 8 XCDs == 0): the 4 quarter-blocks sharing one mb
// (same 6.4KB P gather) land on the same XCD L2.
// Block owns 256 rows staged in LDS (20 KB) + P (6.4 KB); ONE barrier;
// thread (rg, t) computes 16 rows x 4 cols, acc[16]; NT full-row stores.
// ---------------------------------------------------------------------------
#define SPANR 256
#define TPB3  320

__device__ __forceinline__ void fma4(float4& a, float s, const float4& p) {
    a.x = fmaf(s, p.x, a.x);
    a.y = fmaf(s, p.y, a.y);
    a.z = fmaf(s, p.z, a.z);
    a.w = fmaf(s, p.w, a.w);
}

__device__ __forceinline__ void nt_store4(float* dst, const float4& v) {
    f32x4_t w;
    w.x = v.x; w.y = v.y; w.z = v.z; w.w = v.w;
    __builtin_nontemporal_store(w, (f32x4_t*)dst);
}

__global__ __launch_bounds__(TPB3)
void einsum_kernel(const float* __restrict__ inp,  // (M,B,L,S)
                   const float* __restrict__ Pws,  // (M,NR,K,400)
                   const int*   __restrict__ ridx, // (M,B)
                   float*       __restrict__ out)  // (M,B,L,K*S)
{
    __shared__ float Pl[K_ * 400];          // 6400 B   [k][z][s]
    __shared__ float inL[SPANR * 20];       // 20480 B

    // XCD-aware bijective swizzle: 2048 = 8 * 256
    const int bx0     = blockIdx.x;
    const int bx      = (bx0 & 7) * 256 + (bx0 >> 3);
    const int quarter = bx & 3;            // L_/SPANR = 4
    const int mb      = bx >> 2;           // 0..511
    const int mm      = mb >> 8;
    const int tid     = threadIdx.x;
    const int t       = tid % 20;
    const int rg      = tid / 20;          // 0..15
    const int k       = t / 5;
    const int s0      = (t % 5) * 4;

    const int r = ridx[mb];                // block-uniform

    // ---- stage P (1600 floats) and 256 input rows (5120 floats), coalesced ----
    {
        const float4* Psrc = (const float4*)(Pws + ((size_t)(mm * NR_ + r) * K_) * 400);
        float4* Pd = (float4*)Pl;
        Pd[tid] = Psrc[tid];
        if (tid < 80) Pd[320 + tid] = Psrc[320 + tid];

        const size_t row0g = (size_t)mb * L_ + (size_t)quarter * SPANR;
        const float4* Isrc = (const float4*)(inp + row0g * 20);
        float4* Id = (float4*)inL;
        #pragma unroll
        for (int q = 0; q < 4; ++q) Id[tid + q * TPB3] = Isrc[tid + q * TPB3];
    }
    __syncthreads();                       // the ONLY barrier

    const size_t row0 = (size_t)mb * L_ + (size_t)quarter * SPANR;
    float* ob = out + row0 * 80 + k * 20 + s0;
    const float* Pk = Pl + k * 400 + s0;   // + z*20 per z

    float4 acc[16];
    #pragma unroll
    for (int rr = 0; rr < 16; ++rr) acc[rr] = make_float4(0.f, 0.f, 0.f, 0.f);

    #pragma unroll
    for (int z4 = 0; z4 < 5; ++z4) {
        const float4 p0 = *(const float4*)(Pk + (z4 * 4 + 0) * 20);
        const float4 p1 = *(const float4*)(Pk + (z4 * 4 + 1) * 20);
        const float4 p2 = *(const float4*)(Pk + (z4 * 4 + 2) * 20);
        const float4 p3 = *(const float4*)(Pk + (z4 * 4 + 3) * 20);
        #pragma unroll
        for (int rr = 0; rr < 16; ++rr) {
            const int l = rg + rr * 16;
            const float4 av = *(const float4*)(inL + l * 20 + z4 * 4);
            fma4(acc[rr], av.x, p0);
            fma4(acc[rr], av.y, p1);
            fma4(acc[rr], av.z, p2);
            fma4(acc[rr], av.w, p3);
        }
    }

    #pragma unroll
    for (int rr = 0; rr < 16; ++rr) {
        const int l = rg + rr * 16;
        nt_store4(ob + (size_t)l * 80, acc[rr]);
    }
}

// ---------------------------------------------------------------------------
extern "C" void kernel_launch(void* const* d_in, const int* in_sizes, int n_in,
                              void* d_out, int out_size, void* d_ws, size_t ws_size,
                              hipStream_t stream) {
    const float* inp   = (const float*)d_in[0];  // (M,B,L,S)
    const float* tauk  = (const float*)d_in[1];  // (M,NR)
    const float* exch  = (const float*)d_in[2];  // (M,K,S,S)
    const float* equil = (const float*)d_in[3];  // (M,K,S)
    const float* pmrk  = (const float*)d_in[4];  // (M,K)
    const int*   ridx  = (const int*)d_in[5];    // (M,B)
    float* outp = (float*)d_out;

    float* Qpow = (float*)d_ws;                          // 89.6 KB
    float* Pws  = Qpow + (size_t)M_ * K_ * NTERM * 400;  // 1.28 MB

    qpow_kernel<<<M_ * K_, 512, 0, stream>>>(exch, equil, Qpow);
    pbuild_kernel<<<M_ * NR_ * K_, 512, 0, stream>>>(Qpow, tauk, pmrk, Pws);
    einsum_kernel<<<M_ * B_ * (L_ / SPANR), TPB3, 0, stream>>>(inp, Pws, ridx, outp);
}

// Round 18
// 55.272 us; speedup vs baseline: 1.8742x; 1.0502x over previous
//
#include <hip/hip_runtime.h>
#include <math.h>

#define M_  2
#define B_  256
#define L_  1024
#define K_  4
#define S_  20
#define NR_ 100
#define NTERM 7   // Taylor terms T_1..T_7 ; ||mu*Q||inf <= 0.13 -> rem ~2e-11

typedef float f32x4_t __attribute__((ext_vector_type(4)));

__device__ __forceinline__ float softplusf(float x) {
    return x > 20.0f ? x : log1pf(expf(x));
}

// ---------------------------------------------------------------------------
// Kernel 1: per (m,k), compute normalized Q, store T_n = Q^n/n!, n=1..NTERM.
// 8 blocks (the serial chain lives here only). [R16 lesson: do NOT fuse the
// 100-r loop into this 8-block kernel -- latency-bound on 8 CUs, ~+44us.]
// ---------------------------------------------------------------------------
__global__ __launch_bounds__(512)
void qpow_kernel(const float* __restrict__ exch,   // (M,K,S,S)
                 const float* __restrict__ equil,  // (M,K,S)
                 float*       __restrict__ Qpow)   // (M,K,NTERM,400)
{
    __shared__ float sQ[400];
    __shared__ float sT[2][400];
    __shared__ float sRow[20];

    const int blk = blockIdx.x;          // mm*K_ + kk
    const int kk = blk % K_;
    const int mm = blk / K_;
    const int tid = threadIdx.x;
    const bool act = tid < 400;
    const int i = tid / 20;
    const int j = tid - i * 20;

    float p[20];
    float Q0 = 0.0f, rowsum = 0.0f;

    if (act) {
        const float* eq = equil + (mm * K_ + kk) * S_;
        float mx = eq[0];
        #pragma unroll
        for (int z = 1; z < 20; ++z) mx = fmaxf(mx, eq[z]);
        float s = 0.0f;
        #pragma unroll
        for (int z = 0; z < 20; ++z) { p[z] = expf(eq[z] - mx); s += p[z]; }
        const float inv = 1.0f / s;
        #pragma unroll
        for (int z = 0; z < 20; ++z) p[z] *= inv;

        const float* Kx = exch + (mm * K_ + kk) * S_ * S_;
        float R = (i == j) ? 0.0f : softplusf(0.5f * (Kx[i * 20 + j] + Kx[j * 20 + i]));
        Q0 = R * p[j];
        sQ[tid] = Q0;
    }
    __syncthreads();

    if (act) {
        rowsum = 0.0f;
        #pragma unroll
        for (int z = 0; z < 20; ++z) rowsum += sQ[i * 20 + z];
        if (j == 0) sRow[i] = rowsum;
    }
    __syncthreads();

    float* Tout = Qpow + (size_t)blk * (NTERM * 400);
    if (act) {
        float mue = 0.0f;
        #pragma unroll
        for (int z = 0; z < 20; ++z) mue += p[z] * sRow[z];
        float q = (Q0 - ((i == j) ? rowsum : 0.0f)) / fmaxf(mue, 1e-16f);
        sQ[tid] = q;
        sT[0][tid] = q;
        Tout[tid] = q;       // T_1 = Q
    }
    __syncthreads();

    int cur = 0;
    for (int n = 2; n <= NTERM; ++n) {
        if (act) {
            float acc = 0.0f;
            #pragma unroll
            for (int z = 0; z < 20; ++z) acc += sT[cur][i * 20 + z] * sQ[z * 20 + j];
            acc /= (float)n;
            sT[cur ^ 1][tid] = acc;
            Tout[(n - 1) * 400 + tid] = acc;   // T_n = Q^n / n!
        }
        __syncthreads();
        cur ^= 1;
    }
}

// ---------------------------------------------------------------------------
// Kernel 2: P[m,r,k] = I + sum_n mu^n T_n  (linear combo, no matmuls).
// 800 blocks -- wide and parallel (beats the fused producer by ~44us).
// ---------------------------------------------------------------------------
__global__ __launch_bounds__(512)
void pbuild_kernel(const float* __restrict__ Qpow,  // (M,K,NTERM,400)
                   const float* __restrict__ tauk,  // (M,NR)
                   const float* __restrict__ pmrk,  // (M,K)
                   float*       __restrict__ Pws)   // (M,NR,K,400)
{
    const int blk = blockIdx.x;          // mm*NR*K + rr*K + kk
    const int kk = blk % K_;
    const int rr = (blk / K_) % NR_;
    const int mm = blk / (K_ * NR_);
    const int tid = threadIdx.x;
    if (tid >= 400) return;

    const float mu = softplusf(tauk[mm * NR_ + rr]) * softplusf(pmrk[mm * K_ + kk]);
    const float* T = Qpow + ((size_t)(mm * K_ + kk) * NTERM) * 400 + tid;

    float acc = (tid % 21 == 0) ? 1.0f : 0.0f;   // identity
    float mp = mu;
    #pragma unroll
    for (int n = 0; n < NTERM; ++n) { acc = fmaf(mp, T[n * 400], acc); mp *= mu; }
    Pws[(size_t)blk * 400 + tid] = acc;
}

// ---------------------------------------------------------------------------
// Kernel 3: champion einsum; SINGLE CHANGE vs R17: staging (P + input) via
// global_load_lds width-16 DMA (linear LDS dest = wave-uniform base +
// lane*16 per m104) -- deletes ~9 ds_write_b128 + 8 VGPR-round-trip loads
// per thread from the staging phase.
// Block owns 256 rows in LDS (20 KB) + P (6.4 KB); ONE barrier; thread
// (rg, t) computes 16 rows x 4 cols, acc[16]; NT full-row stores.
// ---------------------------------------------------------------------------
#define SPANR 256
#define TPB3  320

__device__ __forceinline__ void fma4(float4& a, float s, const float4& p) {
    a.x = fmaf(s, p.x, a.x);
    a.y = fmaf(s, p.y, a.y);
    a.z = fmaf(s, p.z, a.z);
    a.w = fmaf(s, p.w, a.w);
}

__device__ __forceinline__ void nt_store4(float* dst, const float4& v) {
    f32x4_t w;
    w.x = v.x; w.y = v.y; w.z = v.z; w.w = v.w;
    __builtin_nontemporal_store(w, (f32x4_t*)dst);
}

__device__ __forceinline__ void dma16(const void* gsrc, void* lds_base) {
    __builtin_amdgcn_global_load_lds(
        (const __attribute__((address_space(1))) void*)gsrc,
        (__attribute__((address_space(3))) void*)lds_base,
        16, 0, 0);
}

__global__ __launch_bounds__(TPB3)
void einsum_kernel(const float* __restrict__ inp,  // (M,B,L,S)
                   const float* __restrict__ Pws,  // (M,NR,K,400)
                   const int*   __restrict__ ridx, // (M,B)
                   float*       __restrict__ out)  // (M,B,L,K*S)
{
    __shared__ float Pl[K_ * 400];          // 6400 B   [k][z][s]
    __shared__ float inL[SPANR * 20];       // 20480 B

    // XCD-aware bijective swizzle: 2048 = 8 * 256 (neutral, kept)
    const int bx0     = blockIdx.x;
    const int bx      = (bx0 & 7) * 256 + (bx0 >> 3);
    const int quarter = bx & 3;            // L_/SPANR = 4
    const int mb      = bx >> 2;           // 0..511
    const int mm      = mb >> 8;
    const int tid     = threadIdx.x;
    const int wave    = tid >> 6;
    const int lane    = tid & 63;
    const int t       = tid % 20;
    const int rg      = tid / 20;          // 0..15
    const int k       = t / 5;
    const int s0      = (t % 5) * 4;

    const int r = ridx[mb];                // block-uniform

    // ---- stage input (20 KB) + P (6.4 KB) via global_load_lds DMA ----
    {
        const size_t row0g = (size_t)mb * L_ + (size_t)quarter * SPANR;
        const char* gin = (const char*)(inp + row0g * 20);
        char* lin = (char*)inL;
        // 20 KB = 20 wave-chunks of 1 KB; 5 waves x 4 issues
        #pragma unroll
        for (int q = 0; q < 4; ++q) {
            const int off = (q * 5 + wave) * 1024;
            dma16(gin + off + lane * 16, lin + off);
        }
        // P: 6400 B = 400 x 16B chunks
        const char* gp = (const char*)(Pws + ((size_t)(mm * NR_ + r) * K_) * 400);
        char* lp = (char*)Pl;
        {
            const int off = wave * 1024;           // chunks 0..319
            dma16(gp + off + lane * 16, lp + off);
        }
        if (tid < 80) {                            // chunks 320..399
            const int off = 5120 + wave * 1024;    // wave 0 full, wave 1 lanes 0..15
            dma16(gp + off + lane * 16, lp + off);
        }
    }
    __syncthreads();   // compiler drains vmcnt(0) before s_barrier

    const size_t row0 = (size_t)mb * L_ + (size_t)quarter * SPANR;
    float* ob = out + row0 * 80 + k * 20 + s0;
    const float* Pk = Pl + k * 400 + s0;   // + z*20 per z

    float4 acc[16];
    #pragma unroll
    for (int rr = 0; rr < 16; ++rr) acc[rr] = make_float4(0.f, 0.f, 0.f, 0.f);

    #pragma unroll
    for (int z4 = 0; z4 < 5; ++z4) {
        const float4 p0 = *(const float4*)(Pk + (z4 * 4 + 0) * 20);
        const float4 p1 = *(const float4*)(Pk + (z4 * 4 + 1) * 20);
        const float4 p2 = *(const float4*)(Pk + (z4 * 4 + 2) * 20);
        const float4 p3 = *(const float4*)(Pk + (z4 * 4 + 3) * 20);
        #pragma unroll
        for (int rr = 0; rr < 16; ++rr) {
            const int l = rg + rr * 16;
            const float4 av = *(const float4*)(inL + l * 20 + z4 * 4);
            fma4(acc[rr], av.x, p0);
            fma4(acc[rr], av.y, p1);
            fma4(acc[rr], av.z, p2);
            fma4(acc[rr], av.w, p3);
        }
    }

    #pragma unroll
    for (int rr = 0; rr < 16; ++rr) {
        const int l = rg + rr * 16;
        nt_store4(ob + (size_t)l * 80, acc[rr]);
    }
}

// ---------------------------------------------------------------------------
extern "C" void kernel_launch(void* const* d_in, const int* in_sizes, int n_in,
                              void* d_out, int out_size, void* d_ws, size_t ws_size,
                              hipStream_t stream) {
    const float* inp   = (const float*)d_in[0];  // (M,B,L,S)
    const float* tauk  = (const float*)d_in[1];  // (M,NR)
    const float* exch  = (const float*)d_in[2];  // (M,K,S,S)
    const float* equil = (const float*)d_in[3];  // (M,K,S)
    const float* pmrk  = (const float*)d_in[4];  // (M,K)
    const int*   ridx  = (const int*)d_in[5];    // (M,B)
    float* outp = (float*)d_out;

    float* Qpow = (float*)d_ws;                          // 89.6 KB
    float* Pws  = Qpow + (size_t)M_ * K_ * NTERM * 400;  // 1.28 MB

    qpow_kernel<<<M_ * K_, 512, 0, stream>>>(exch, equil, Qpow);
    pbuild_kernel<<<M_ * NR_ * K_, 512, 0, stream>>>(Qpow, tauk, pmrk, Pws);
    einsum_kernel<<<M_ * B_ * (L_ / SPANR), TPB3, 0, stream>>>(inp, Pws, ridx, outp);
}